// Round 6
// baseline (200.346 us; speedup 1.0000x reference)
//
#include <hip/hip_runtime.h>
#include <hip/hip_bf16.h>
#include <math.h>

#define N_NODES 50000
#define N_EDGES 400000
#define IN_DIM 256
#define OUT_DIM 64
#define HEADS 2
#define ATTN_HIDDEN 64
#define ALPHA_SLOPE 0.2f
#define TEMP 0.55f
#define NHF 128   // HEADS*OUT_DIM
#define ZDIM 384  // Wh(128) | Us(128) | Ud(128)

typedef __bf16 bf16x8 __attribute__((ext_vector_type(8)));
typedef float f32x4 __attribute__((ext_vector_type(4)));

__device__ __forceinline__ ushort f2bf(float f) {
    unsigned u = __float_as_uint(f);
    u = (u + 0x7fffu + ((u >> 16) & 1u)) >> 16;
    return (ushort)u;
}
__device__ __forceinline__ unsigned pack2(float a, float b) {
    return (unsigned)f2bf(a) | ((unsigned)f2bf(b) << 16);
}
__device__ __forceinline__ float bfl(unsigned u) { return __uint_as_float(u << 16); }
__device__ __forceinline__ float bfh(unsigned u) { return __uint_as_float(u & 0xffff0000u); }

// ---------------------------------------------------------------------------
// K1: build Wct (bf16, [n][k]) AND seg[] (segment starts) in one launch.
//   blocks [0,384):   Wct as before
//   blocks [384,580): seg[n] = lower_bound(dst, n) for n = (b-384)*256 + t
// ---------------------------------------------------------------------------
__global__ __launch_bounds__(256) void k_combine(const float* __restrict__ W,
                                                 const float* __restrict__ Wa,
                                                 ushort* __restrict__ Wct,
                                                 const int* __restrict__ dst,
                                                 int* __restrict__ seg) {
    __shared__ float col[64];
    const int b = blockIdx.x;
    const int t = threadIdx.x;
    if (b >= ZDIM) {   // segstart path
        int n = (b - ZDIM) * 256 + t;
        if (n > N_NODES) return;
        int lo = 0, hi = N_EDGES;
        while (lo < hi) {
            int mid = (lo + hi) >> 1;
            if (dst[mid] < n) lo = mid + 1; else hi = mid;
        }
        seg[n] = lo;
        return;
    }
    const int n = b;
    if (n < 128) {
        Wct[(size_t)n * 256 + t] = f2bf(W[(size_t)t * NHF + n]);
        return;
    }
    const int part = (n - 128) >> 7;       // 0 = src-half, 1 = dst-half
    const int idx = (n - 128) & 127;
    const int h = idx >> 6;
    const int c = idx & 63;
    const int fb = part ? 64 : 0;
    if (t < 64) col[t] = Wa[(size_t)h * 8192 + (size_t)(fb + t) * 64 + c];
    __syncthreads();
    const float* wr = W + (size_t)t * NHF + h * 64;
    float acc = 0.f;
#pragma unroll
    for (int f = 0; f < 64; f++) acc += wr[f] * col[f];
    Wct[(size_t)n * 256 + t] = f2bf(acc);
}

// ---------------------------------------------------------------------------
// K2: Z[50000,384] = x @ Wcomb. Block: 64(M) x 384(N), 4 waves x 16 rows,
// K-loop 8 x 32. B in LDS in MFMA-fragment order (every ds access is
// base + lane*16 -> zero bank conflicts), double-buffered, 1 barrier/iter.
// A loaded global->reg per wave (fp32->bf16 pack), never touches LDS.
// Frag maps (verified): A[m=lane&15][k=(lane>>4)*8+j]; D row=(lane>>4)*4+rr,
// col=lane&15.
// ---------------------------------------------------------------------------
__global__ __launch_bounds__(256, 3) void k_gemm(const float* __restrict__ x,
                                                 const ushort* __restrict__ Wct,
                                                 ushort* __restrict__ Zb) {
    // 2 buffers x 24 c-tiles x 64 lanes x 16B = 2 x 24KB
    __shared__ __align__(16) ushort Bs[2][12288];
    const int t = threadIdx.x;
    const int w = t >> 6, lane = t & 63;
    const int q = lane >> 4, r16 = lane & 15;
    const int row0 = blockIdx.x * 64;

    // B staging map: slice j covers lds idx = j*256+t <-> (c = idx>>6, lj = idx&63)
    // global element: Wct[(c*16 + (lj&15)) * 256 + (lj>>4)*8 + k0]
    int boff[6];
#pragma unroll
    for (int j = 0; j < 6; j++) {
        int idx = j * 256 + t;
        int c = idx >> 6, lj = idx & 63;
        boff[j] = (c * 16 + (lj & 15)) * 256 + (lj >> 4) * 8;
    }
    const int arow = row0 + w * 16 + r16;
    const bool avalid = arow < N_NODES;
    const float* xp = x + (size_t)arow * IN_DIM + q * 8;

    f32x4 acc[24];
#pragma unroll
    for (int c = 0; c < 24; c++) acc[c] = (f32x4){0.f, 0.f, 0.f, 0.f};

    // ---- prologue: fetch k-chunk 0, stage into buf 0
    uint4 bv[6];
#pragma unroll
    for (int j = 0; j < 6; j++) bv[j] = *(const uint4*)(Wct + boff[j]);
    float4 av0 = make_float4(0.f, 0.f, 0.f, 0.f), av1 = av0;
    if (avalid) { av0 = *(const float4*)xp; av1 = *(const float4*)(xp + 4); }
#pragma unroll
    for (int j = 0; j < 6; j++) *(uint4*)&Bs[0][(j * 256 + t) * 8] = bv[j];
    __syncthreads();

    for (int k = 0; k < 8; k++) {
        const int cur = k & 1;
        // build current A fragment from regs
        uint4 afp;
        afp.x = pack2(av0.x, av0.y); afp.y = pack2(av0.z, av0.w);
        afp.z = pack2(av1.x, av1.y); afp.w = pack2(av1.z, av1.w);
        const bf16x8 af = *(const bf16x8*)&afp;
        // issue next chunk's global loads (land during MFMA phase)
        if (k < 7) {
            const int kn = (k + 1) * 32;
#pragma unroll
            for (int j = 0; j < 6; j++) bv[j] = *(const uint4*)(Wct + boff[j] + kn);
            if (avalid) {
                av0 = *(const float4*)(xp + kn);
                av1 = *(const float4*)(xp + kn + 4);
            }
        }
        // MFMA phase: 24 conflict-free lane-linear b128 reads
#pragma unroll
        for (int c = 0; c < 24; c++) {
            const bf16x8 bf = *(const bf16x8*)&Bs[cur][c * 512 + lane * 8];
            acc[c] = __builtin_amdgcn_mfma_f32_16x16x32_bf16(af, bf, acc[c], 0, 0, 0);
        }
        // stage next chunk into alternate buffer
        if (k < 7) {
#pragma unroll
            for (int j = 0; j < 6; j++) *(uint4*)&Bs[1 - cur][(j * 256 + t) * 8] = bv[j];
        }
        __syncthreads();
    }
#pragma unroll
    for (int c = 0; c < 24; c++) {
#pragma unroll
        for (int rr = 0; rr < 4; rr++) {
            int row = row0 + w * 16 + q * 4 + rr;
            if (row < N_NODES)
                Zb[(size_t)row * ZDIM + c * 16 + r16] = f2bf(acc[c][rr]);
        }
    }
}

// ---------------------------------------------------------------------------
// K3: fused logits + online segment-softmax + weighted accumulate.
// 16 lanes per node, 4 nodes per wave, 16 nodes per block.
// ---------------------------------------------------------------------------
__global__ __launch_bounds__(256) void k_fused(const ushort* __restrict__ Zb,
                                               const float* __restrict__ avec,
                                               const int* __restrict__ src,
                                               const int* __restrict__ seg,
                                               float* __restrict__ out) {
    const int lane = threadIdx.x & 63;
    const int wv = threadIdx.x >> 6;
    const int g = lane >> 4, l16 = lane & 15;
    const int n = blockIdx.x * 16 + wv * 4 + g;
    if (n >= N_NODES) return;
    const int choff = 8 * l16;

    const float4 af0 = *(const float4*)(avec + choff);
    const float4 af1 = *(const float4*)(avec + choff + 4);
    const float a[8] = {af0.x, af0.y, af0.z, af0.w, af1.x, af1.y, af1.z, af1.w};

    const uint4 udv = *(const uint4*)(Zb + (size_t)n * ZDIM + 256 + choff);
    const float ud[8] = {bfl(udv.x), bfh(udv.x), bfl(udv.y), bfh(udv.y),
                         bfl(udv.z), bfh(udv.z), bfl(udv.w), bfh(udv.w)};

    const int e0 = seg[n], e1 = seg[n + 1];
    float m = -INFINITY, l = 0.f;
    float acc[8] = {0.f, 0.f, 0.f, 0.f, 0.f, 0.f, 0.f, 0.f};

    uint4 us = make_uint4(0, 0, 0, 0), wh = us;
    if (e0 < e1) {
        const int s = src[e0];
        us = *(const uint4*)(Zb + (size_t)s * ZDIM + 128 + choff);
        wh = *(const uint4*)(Zb + (size_t)s * ZDIM + choff);
    }
    for (int e = e0; e < e1; e++) {
        const uint4 cus = us, cwh = wh;
        if (e + 1 < e1) {                 // prefetch next edge during reduce
            const int sn = src[e + 1];
            us = *(const uint4*)(Zb + (size_t)sn * ZDIM + 128 + choff);
            wh = *(const uint4*)(Zb + (size_t)sn * ZDIM + choff);
        }
        float p;
        {
            float v0, v1, s0, s1;
            v0 = bfl(cus.x) + ud[0]; v1 = bfh(cus.x) + ud[1];
            s0 = fmaxf(v0, ALPHA_SLOPE * v0); s1 = fmaxf(v1, ALPHA_SLOPE * v1);
            p = s0 * a[0] + s1 * a[1];
            v0 = bfl(cus.y) + ud[2]; v1 = bfh(cus.y) + ud[3];
            s0 = fmaxf(v0, ALPHA_SLOPE * v0); s1 = fmaxf(v1, ALPHA_SLOPE * v1);
            p += s0 * a[2] + s1 * a[3];
            v0 = bfl(cus.z) + ud[4]; v1 = bfh(cus.z) + ud[5];
            s0 = fmaxf(v0, ALPHA_SLOPE * v0); s1 = fmaxf(v1, ALPHA_SLOPE * v1);
            p += s0 * a[4] + s1 * a[5];
            v0 = bfl(cus.w) + ud[6]; v1 = bfh(cus.w) + ud[7];
            s0 = fmaxf(v0, ALPHA_SLOPE * v0); s1 = fmaxf(v1, ALPHA_SLOPE * v1);
            p += s0 * a[6] + s1 * a[7];
        }
        p += __shfl_xor(p, 1, 64);
        p += __shfl_xor(p, 2, 64);
        p += __shfl_xor(p, 4, 64);        // lanes 0-7: head0 logit, 8-15: head1
        const float logit = p * (1.0f / TEMP);
        const float nm = fmaxf(m, logit);
        const float sc = __expf(m - nm);       // first iter: exp(-inf)=0
        const float wgt = __expf(logit - nm);
        l = l * sc + wgt;
        acc[0] = acc[0] * sc + wgt * bfl(cwh.x);
        acc[1] = acc[1] * sc + wgt * bfh(cwh.x);
        acc[2] = acc[2] * sc + wgt * bfl(cwh.y);
        acc[3] = acc[3] * sc + wgt * bfh(cwh.y);
        acc[4] = acc[4] * sc + wgt * bfl(cwh.z);
        acc[5] = acc[5] * sc + wgt * bfh(cwh.z);
        acc[6] = acc[6] * sc + wgt * bfl(cwh.w);
        acc[7] = acc[7] * sc + wgt * bfh(cwh.w);
        m = nm;
    }
    const float inv = 0.5f / (l + 1e-9f);      // ref 1/(sum+1e-9) + head-mean
#pragma unroll
    for (int j = 0; j < 8; j++) {
        const float v = acc[j] * inv;
        acc[j] = v + __shfl_xor(v, 8, 64);     // head0[c] + head1[c]
    }
    if (l16 < 8) {
        float4 o0 = make_float4(acc[0], acc[1], acc[2], acc[3]);
        float4 o1 = make_float4(acc[4], acc[5], acc[6], acc[7]);
        float* op = out + (size_t)n * 64 + choff;
        *(float4*)op = o0;
        *(float4*)(op + 4) = o1;
    }
}

// ---------------------------------------------------------------------------
extern "C" void kernel_launch(void* const* d_in, const int* in_sizes, int n_in,
                              void* d_out, int out_size, void* d_ws, size_t ws_size,
                              hipStream_t stream) {
    const float* x    = (const float*)d_in[0];
    const float* W    = (const float*)d_in[1];
    const float* Wa   = (const float*)d_in[2];
    const float* avec = (const float*)d_in[3];
    const int*   src  = (const int*)d_in[4];
    const int*   dst  = (const int*)d_in[5];
    float* out = (float*)d_out;

    ushort* Zb  = (ushort*)d_ws;                       // 19,200,000 bf16 = 38.4 MB
    ushort* Wct = Zb + 19200000;                       // 98,304 bf16
    int*    seg = (int*)((char*)d_ws + 38596608);      // 50,001 ints

    const int seg_blocks = (N_NODES + 1 + 255) / 256;  // 196
    k_combine <<<ZDIM + seg_blocks, 256, 0, stream>>>(W, Wa, Wct, dst, seg);
    k_gemm    <<<(N_NODES + 63) / 64, 256, 0, stream>>>(x, Wct, Zb);
    k_fused   <<<(N_NODES + 15) / 16, 256, 0, stream>>>(Zb, avec, src, seg, out);
}

// Round 7
// 173.375 us; speedup vs baseline: 1.1556x; 1.1556x over previous
//
#include <hip/hip_runtime.h>
#include <hip/hip_bf16.h>
#include <math.h>

#define N_NODES 50000
#define N_EDGES 400000
#define IN_DIM 256
#define OUT_DIM 64
#define HEADS 2
#define ATTN_HIDDEN 64
#define ALPHA_SLOPE 0.2f
#define TEMP 0.55f
#define NHF 128   // HEADS*OUT_DIM
#define ZDIM 384  // Wh(128) | Us(128) | Ud(128)

typedef __bf16 bf16x8 __attribute__((ext_vector_type(8)));
typedef float f32x4 __attribute__((ext_vector_type(4)));

__device__ __forceinline__ ushort f2bf(float f) {
    unsigned u = __float_as_uint(f);
    u = (u + 0x7fffu + ((u >> 16) & 1u)) >> 16;
    return (ushort)u;
}
__device__ __forceinline__ unsigned pack2(float a, float b) {
    return (unsigned)f2bf(a) | ((unsigned)f2bf(b) << 16);
}
__device__ __forceinline__ float bfl(unsigned u) { return __uint_as_float(u << 16); }
__device__ __forceinline__ float bfh(unsigned u) { return __uint_as_float(u & 0xffff0000u); }

// ---------------------------------------------------------------------------
// K1: build Wctf — the combined weight matrix in MFMA B-FRAGMENT ORDER — and
// seg[] in one launch.
//   Value for (n,k): n<128: W[k,n]; n>=128: sum_f W[k,h,f]*Wa[h,fb+f,c].
//   Fragment position for (n,k): c=n>>4, r16=n&15, kc=k>>5, q=(k>>3)&3, j=k&7
//     pos = ((c*8+kc)*64 + q*16 + r16)*8 + j
//   so k_gemm's B load at (c,kc) is base + lane*8 — lane-linear, coalesced.
// ---------------------------------------------------------------------------
__global__ __launch_bounds__(256) void k_combine(const float* __restrict__ W,
                                                 const float* __restrict__ Wa,
                                                 ushort* __restrict__ Wctf,
                                                 const int* __restrict__ dst,
                                                 int* __restrict__ seg) {
    __shared__ float col[64];
    const int b = blockIdx.x;
    const int t = threadIdx.x;
    if (b >= ZDIM) {   // segstart path
        int n = (b - ZDIM) * 256 + t;
        if (n > N_NODES) return;
        int lo = 0, hi = N_EDGES;
        while (lo < hi) {
            int mid = (lo + hi) >> 1;
            if (dst[mid] < n) lo = mid + 1; else hi = mid;
        }
        seg[n] = lo;
        return;
    }
    const int n = b;      // output column 0..383
    const int k = t;      // input dim 0..255
    // fragment-order position
    const int c = n >> 4, r16 = n & 15;
    const int kc = k >> 5, q = (k >> 3) & 3, j = k & 7;
    const size_t pos = (size_t)(((c * 8 + kc) * 64 + q * 16 + r16)) * 8 + j;

    float val;
    if (n < 128) {
        val = W[(size_t)k * NHF + n];
    } else {
        const int part = (n - 128) >> 7;       // 0 = src-half, 1 = dst-half
        const int idx = (n - 128) & 127;
        const int h = idx >> 6;
        const int cc = idx & 63;
        const int fb = part ? 64 : 0;
        if (t < 64) col[t] = Wa[(size_t)h * 8192 + (size_t)(fb + t) * 64 + cc];
        __syncthreads();
        const float* wr = W + (size_t)k * NHF + h * 64;
        float acc = 0.f;
#pragma unroll
        for (int f = 0; f < 64; f++) acc += wr[f] * col[f];
        val = acc;
    }
    Wctf[pos] = f2bf(val);
}

// ---------------------------------------------------------------------------
// K2: Z[50000,384] = x @ Wcomb. NO LDS, NO BARRIERS. Wave-independent
// streaming: each wave owns 32 rows (2 m-tiles x 16), loops kc=0..7.
// A: coalesced float4 pair per m-tile straight from x, packed to bf16 in
// regs. B: lane-linear bf16x8 fragment loads from L2-resident Wctf (192KB).
// 48 MFMAs per k-chunk per wave. acc = 2x24 f32x4 = 192 VGPRs.
// A frag: A[m=lane&15][k=(lane>>4)*8+j]; D: row=(lane>>4)*4+rr, col=lane&15.
// ---------------------------------------------------------------------------
__global__ __launch_bounds__(256, 2) void k_gemm(const float* __restrict__ x,
                                                 const ushort* __restrict__ Wctf,
                                                 ushort* __restrict__ Zb) {
    const int t = threadIdx.x;
    const int w = t >> 6, lane = t & 63;
    const int q = lane >> 4, r16 = lane & 15;
    const int wid = blockIdx.x * 4 + w;
    const int row0 = wid * 32;
    if (row0 >= N_NODES) return;

    // A source rows (clamp tail; stores are guarded)
    int rA0 = row0 + r16;
    int rA1 = row0 + 16 + r16;
    rA0 = rA0 < N_NODES ? rA0 : N_NODES - 1;
    rA1 = rA1 < N_NODES ? rA1 : N_NODES - 1;
    const float* xp0 = x + (size_t)rA0 * IN_DIM + q * 8;
    const float* xp1 = x + (size_t)rA1 * IN_DIM + q * 8;
    const ushort* bp = Wctf + lane * 8;

    f32x4 acc[2][24];
#pragma unroll
    for (int mt = 0; mt < 2; mt++)
#pragma unroll
        for (int c = 0; c < 24; c++) acc[mt][c] = (f32x4){0.f, 0.f, 0.f, 0.f};

#pragma unroll 1
    for (int kc = 0; kc < 8; kc++) {
        const float4 a00 = *(const float4*)(xp0 + kc * 32);
        const float4 a01 = *(const float4*)(xp0 + kc * 32 + 4);
        const float4 a10 = *(const float4*)(xp1 + kc * 32);
        const float4 a11 = *(const float4*)(xp1 + kc * 32 + 4);
        uint4 p0, p1;
        p0.x = pack2(a00.x, a00.y); p0.y = pack2(a00.z, a00.w);
        p0.z = pack2(a01.x, a01.y); p0.w = pack2(a01.z, a01.w);
        p1.x = pack2(a10.x, a10.y); p1.y = pack2(a10.z, a10.w);
        p1.z = pack2(a11.x, a11.y); p1.w = pack2(a11.z, a11.w);
        const bf16x8 af0 = *(const bf16x8*)&p0;
        const bf16x8 af1 = *(const bf16x8*)&p1;
        const ushort* bk = bp + kc * 512;
#pragma unroll
        for (int c = 0; c < 24; c++) {
            const bf16x8 bf = *(const bf16x8*)(bk + c * 4096);
            acc[0][c] = __builtin_amdgcn_mfma_f32_16x16x32_bf16(af0, bf, acc[0][c], 0, 0, 0);
            acc[1][c] = __builtin_amdgcn_mfma_f32_16x16x32_bf16(af1, bf, acc[1][c], 0, 0, 0);
        }
    }
#pragma unroll
    for (int mt = 0; mt < 2; mt++)
#pragma unroll
        for (int c = 0; c < 24; c++)
#pragma unroll
            for (int rr = 0; rr < 4; rr++) {
                const int row = row0 + mt * 16 + q * 4 + rr;
                if (row < N_NODES)
                    Zb[(size_t)row * ZDIM + c * 16 + r16] = f2bf(acc[mt][c][rr]);
            }
}

// ---------------------------------------------------------------------------
// K3: fused logits + online segment-softmax + weighted accumulate.
// 16 lanes per node, 4 nodes per wave, 16 nodes per block.
// ---------------------------------------------------------------------------
__global__ __launch_bounds__(256) void k_fused(const ushort* __restrict__ Zb,
                                               const float* __restrict__ avec,
                                               const int* __restrict__ src,
                                               const int* __restrict__ seg,
                                               float* __restrict__ out) {
    const int lane = threadIdx.x & 63;
    const int wv = threadIdx.x >> 6;
    const int g = lane >> 4, l16 = lane & 15;
    const int n = blockIdx.x * 16 + wv * 4 + g;
    if (n >= N_NODES) return;
    const int choff = 8 * l16;

    const float4 af0 = *(const float4*)(avec + choff);
    const float4 af1 = *(const float4*)(avec + choff + 4);
    const float a[8] = {af0.x, af0.y, af0.z, af0.w, af1.x, af1.y, af1.z, af1.w};

    const uint4 udv = *(const uint4*)(Zb + (size_t)n * ZDIM + 256 + choff);
    const float ud[8] = {bfl(udv.x), bfh(udv.x), bfl(udv.y), bfh(udv.y),
                         bfl(udv.z), bfh(udv.z), bfl(udv.w), bfh(udv.w)};

    const int e0 = seg[n], e1 = seg[n + 1];
    float m = -INFINITY, l = 0.f;
    float acc[8] = {0.f, 0.f, 0.f, 0.f, 0.f, 0.f, 0.f, 0.f};

    uint4 us = make_uint4(0, 0, 0, 0), wh = us;
    if (e0 < e1) {
        const int s = src[e0];
        us = *(const uint4*)(Zb + (size_t)s * ZDIM + 128 + choff);
        wh = *(const uint4*)(Zb + (size_t)s * ZDIM + choff);
    }
    for (int e = e0; e < e1; e++) {
        const uint4 cus = us, cwh = wh;
        if (e + 1 < e1) {                 // prefetch next edge during reduce
            const int sn = src[e + 1];
            us = *(const uint4*)(Zb + (size_t)sn * ZDIM + 128 + choff);
            wh = *(const uint4*)(Zb + (size_t)sn * ZDIM + choff);
        }
        float p;
        {
            float v0, v1, s0, s1;
            v0 = bfl(cus.x) + ud[0]; v1 = bfh(cus.x) + ud[1];
            s0 = fmaxf(v0, ALPHA_SLOPE * v0); s1 = fmaxf(v1, ALPHA_SLOPE * v1);
            p = s0 * a[0] + s1 * a[1];
            v0 = bfl(cus.y) + ud[2]; v1 = bfh(cus.y) + ud[3];
            s0 = fmaxf(v0, ALPHA_SLOPE * v0); s1 = fmaxf(v1, ALPHA_SLOPE * v1);
            p += s0 * a[2] + s1 * a[3];
            v0 = bfl(cus.z) + ud[4]; v1 = bfh(cus.z) + ud[5];
            s0 = fmaxf(v0, ALPHA_SLOPE * v0); s1 = fmaxf(v1, ALPHA_SLOPE * v1);
            p += s0 * a[4] + s1 * a[5];
            v0 = bfl(cus.w) + ud[6]; v1 = bfh(cus.w) + ud[7];
            s0 = fmaxf(v0, ALPHA_SLOPE * v0); s1 = fmaxf(v1, ALPHA_SLOPE * v1);
            p += s0 * a[6] + s1 * a[7];
        }
        p += __shfl_xor(p, 1, 64);
        p += __shfl_xor(p, 2, 64);
        p += __shfl_xor(p, 4, 64);        // lanes 0-7: head0 logit, 8-15: head1
        const float logit = p * (1.0f / TEMP);
        const float nm = fmaxf(m, logit);
        const float sc = __expf(m - nm);       // first iter: exp(-inf)=0
        const float wgt = __expf(logit - nm);
        l = l * sc + wgt;
        acc[0] = acc[0] * sc + wgt * bfl(cwh.x);
        acc[1] = acc[1] * sc + wgt * bfh(cwh.x);
        acc[2] = acc[2] * sc + wgt * bfl(cwh.y);
        acc[3] = acc[3] * sc + wgt * bfh(cwh.y);
        acc[4] = acc[4] * sc + wgt * bfl(cwh.z);
        acc[5] = acc[5] * sc + wgt * bfh(cwh.z);
        acc[6] = acc[6] * sc + wgt * bfl(cwh.w);
        acc[7] = acc[7] * sc + wgt * bfh(cwh.w);
        m = nm;
    }
    const float inv = 0.5f / (l + 1e-9f);      // ref 1/(sum+1e-9) + head-mean
#pragma unroll
    for (int j = 0; j < 8; j++) {
        const float v = acc[j] * inv;
        acc[j] = v + __shfl_xor(v, 8, 64);     // head0[c] + head1[c]
    }
    if (l16 < 8) {
        float4 o0 = make_float4(acc[0], acc[1], acc[2], acc[3]);
        float4 o1 = make_float4(acc[4], acc[5], acc[6], acc[7]);
        float* op = out + (size_t)n * 64 + choff;
        *(float4*)op = o0;
        *(float4*)(op + 4) = o1;
    }
}

// ---------------------------------------------------------------------------
extern "C" void kernel_launch(void* const* d_in, const int* in_sizes, int n_in,
                              void* d_out, int out_size, void* d_ws, size_t ws_size,
                              hipStream_t stream) {
    const float* x    = (const float*)d_in[0];
    const float* W    = (const float*)d_in[1];
    const float* Wa   = (const float*)d_in[2];
    const float* avec = (const float*)d_in[3];
    const int*   src  = (const int*)d_in[4];
    const int*   dst  = (const int*)d_in[5];
    float* out = (float*)d_out;

    ushort* Zb   = (ushort*)d_ws;                      // 19,200,000 bf16 = 38.4 MB
    ushort* Wctf = Zb + 19200000;                      // 98,304 bf16 (fragment order)
    int*    seg  = (int*)((char*)d_ws + 38596608);     // 50,001 ints

    const int seg_blocks = (N_NODES + 1 + 255) / 256;  // 196
    const int gemm_waves = (N_NODES + 31) / 32;        // 1563
    k_combine <<<ZDIM + seg_blocks, 256, 0, stream>>>(W, Wa, Wctf, dst, seg);
    k_gemm    <<<(gemm_waves + 3) / 4, 256, 0, stream>>>(x, Wctf, Zb);
    k_fused   <<<(N_NODES + 15) / 16, 256, 0, stream>>>(Zb, avec, src, seg, out);
}